// Round 2
// baseline (398.843 us; speedup 1.0000x reference)
//
#include <hip/hip_runtime.h>
#include <math.h>

// Problem constants: B=16384, DMODEL=64, NPTS=1323
#define BATCH   16384
#define DMODEL  64
#define NPTS    1323u
#define TOTAL_PTS (16384u * 1323u)          // 21,676,032 (divisible by 4)
#define STREAM_THREADS (TOTAL_PTS / 4u)     // 5,419,008
#define STREAM_BLOCKS  (STREAM_THREADS / 256u) // 21,168 exactly

// 1.5 * log(2*pi)
#define C_15LOG2PI 2.7568155996140194f

__device__ __forceinline__ float wave_reduce_sum64(float v) {
#pragma unroll
    for (int off = 32; off > 0; off >>= 1)
        v += __shfl_xor(v, off, 64);
    return v;
}

__device__ __forceinline__ float softplus_f(float x) {
    return log1pf(expf(x));   // x in (0,1): no overflow
}
__device__ __forceinline__ float sigmoid_f(float x) {
    return 1.0f / (1.0f + expf(-x));
}

// ---------------- Kernel A: per-row params ----------------
// One wave per row; 4 waves (rows) per block; 4096 blocks.
// Writes 12 floats per row: q0=(m0,m1,m2,iL00) q1=(L10,iL11,L20,L21) q2=(iL22,c,0,0)
__global__ __launch_bounds__(256) void params_kernel(
    const float* __restrict__ rep, const float* __restrict__ Wm,
    const float* __restrict__ bm,  const float* __restrict__ Ws,
    const float* __restrict__ bs,  float* __restrict__ pw)
{
    const int wave = threadIdx.x >> 6;
    const int lane = threadIdx.x & 63;
    const int row  = blockIdx.x * 4 + wave;

    const float r = rep[(size_t)row * DMODEL + lane];

    float d0 = r * Wm[0*64 + lane];
    float d1 = r * Wm[1*64 + lane];
    float d2 = r * Wm[2*64 + lane];
    float s0 = r * Ws[0*64 + lane];
    float s1 = r * Ws[1*64 + lane];
    float s2 = r * Ws[2*64 + lane];
    float s3 = r * Ws[3*64 + lane];
    float s4 = r * Ws[4*64 + lane];
    float s5 = r * Ws[5*64 + lane];

    d0 = wave_reduce_sum64(d0);
    d1 = wave_reduce_sum64(d1);
    d2 = wave_reduce_sum64(d2);
    s0 = wave_reduce_sum64(s0);
    s1 = wave_reduce_sum64(s1);
    s2 = wave_reduce_sum64(s2);
    s3 = wave_reduce_sum64(s3);
    s4 = wave_reduce_sum64(s4);
    s5 = wave_reduce_sum64(s5);

    if (lane == 0) {
        const float m0 = d0 + bm[0];
        const float m1 = d1 + bm[1];
        const float m2 = d2 + bm[2];

        const float L00 = softplus_f(sigmoid_f(s0 + bs[0]));
        const float L10 = sigmoid_f(s1 + bs[1]);
        const float L11 = softplus_f(sigmoid_f(s2 + bs[2]));
        const float L20 = sigmoid_f(s3 + bs[3]);
        const float L21 = sigmoid_f(s4 + bs[4]);
        const float L22 = softplus_f(sigmoid_f(s5 + bs[5]));

        const float c = -(logf(L00) + logf(L11) + logf(L22)) - C_15LOG2PI;

        float4* q = (float4*)(pw + (size_t)row * 12);
        q[0] = make_float4(m0, m1, m2, 1.0f / L00);
        q[1] = make_float4(L10, 1.0f / L11, L20, L21);
        q[2] = make_float4(1.0f / L22, c, 0.0f, 0.0f);
    }
}

// ---------------- Kernel B: pure streaming ----------------
__device__ __forceinline__ float eval_pt(float x, float y, float z,
                                         const float4& q0, const float4& q1,
                                         const float4& q2)
{
    const float e0 = x - q0.x;
    const float e1 = y - q0.y;
    const float e2 = z - q0.z;
    const float z0 = e0 * q0.w;
    const float z1 = fmaf(-q1.x, z0, e1) * q1.y;
    const float z2 = fmaf(-q1.w, z1, fmaf(-q1.z, z0, e2)) * q2.x;
    const float maha = fmaf(z0, z0, fmaf(z1, z1, z2 * z2));
    return __expf(fmaf(-0.5f, maha, q2.y));
}

__global__ __launch_bounds__(256) void stream_kernel(
    const float* __restrict__ dxyz, const float* __restrict__ pw,
    float* __restrict__ out)
{
    const unsigned gid = blockIdx.x * 256u + threadIdx.x;

    const float4* __restrict__ src4 = (const float4*)dxyz + (size_t)gid * 3u;
    const float4 a = src4[0];
    const float4 b = src4[1];
    const float4 c = src4[2];

    const unsigned p0  = gid * 4u;
    const unsigned row = p0 / NPTS;               // magic-mul div by constant
    const unsigned rem = p0 - row * NPTS;

    const float4* __restrict__ q = (const float4*)pw + (size_t)row * 3u;
    const float4 q0 = q[0], q1 = q[1], q2 = q[2];

    float o0, o1, o2, o3;
    if (rem <= NPTS - 4u) {
        // all 4 points in this row (common case)
        o0 = eval_pt(a.x, a.y, a.z, q0, q1, q2);
        o1 = eval_pt(a.w, b.x, b.y, q0, q1, q2);
        o2 = eval_pt(b.z, b.w, c.x, q0, q1, q2);
        o3 = eval_pt(c.y, c.z, c.w, q0, q1, q2);
    } else {
        // spans row boundary: ~1 thread per row boundary
        const float4* __restrict__ qq = (const float4*)pw + (size_t)(row + 1u) * 3u;
        const float4 r0 = qq[0], r1 = qq[1], r2 = qq[2];
        const float4 u0 = (rem + 0u < NPTS) ? q0 : r0;
        const float4 u1 = (rem + 0u < NPTS) ? q1 : r1;
        const float4 u2 = (rem + 0u < NPTS) ? q2 : r2;
        o0 = eval_pt(a.x, a.y, a.z, u0, u1, u2);
        const float4 v0 = (rem + 1u < NPTS) ? q0 : r0;
        const float4 v1 = (rem + 1u < NPTS) ? q1 : r1;
        const float4 v2 = (rem + 1u < NPTS) ? q2 : r2;
        o1 = eval_pt(a.w, b.x, b.y, v0, v1, v2);
        const float4 w0 = (rem + 2u < NPTS) ? q0 : r0;
        const float4 w1 = (rem + 2u < NPTS) ? q1 : r1;
        const float4 w2 = (rem + 2u < NPTS) ? q2 : r2;
        o2 = eval_pt(b.z, b.w, c.x, w0, w1, w2);
        o3 = eval_pt(c.y, c.z, c.w, r0, r1, r2);  // rem+3 >= NPTS here always
    }

    ((float4*)out)[gid] = make_float4(o0, o1, o2, o3);
}

extern "C" void kernel_launch(void* const* d_in, const int* in_sizes, int n_in,
                              void* d_out, int out_size, void* d_ws, size_t ws_size,
                              hipStream_t stream) {
    const float* rep  = (const float*)d_in[0];
    const float* dxyz = (const float*)d_in[1];
    const float* Wm   = (const float*)d_in[2];
    const float* bm   = (const float*)d_in[3];
    const float* Ws   = (const float*)d_in[4];
    const float* bs   = (const float*)d_in[5];
    float* out = (float*)d_out;
    float* pw  = (float*)d_ws;   // 16384 * 12 floats = 786,432 B

    params_kernel<<<BATCH / 4, 256, 0, stream>>>(rep, Wm, bm, Ws, bs, pw);
    stream_kernel<<<STREAM_BLOCKS, 256, 0, stream>>>(dxyz, pw, out);
}

// Round 3
// 385.027 us; speedup vs baseline: 1.0359x; 1.0359x over previous
//
#include <hip/hip_runtime.h>
#include <math.h>

// Problem constants: B=16384, DMODEL=64, NPTS=1323
#define BATCH   16384
#define DMODEL  64
#define NPTS    1323u
#define TOTAL_PTS (16384u * 1323u)            // 21,676,032 (divisible by 4)
#define STREAM_THREADS (TOTAL_PTS / 4u)       // 5,419,008
#define STREAM_BLOCKS  (STREAM_THREADS / 256u) // 21,168 exactly

// 1.5 * log(2*pi)
#define C_15LOG2PI 2.7568155996140194f

__device__ __forceinline__ float wave_reduce_sum64(float v) {
#pragma unroll
    for (int off = 32; off > 0; off >>= 1)
        v += __shfl_xor(v, off, 64);
    return v;
}

__device__ __forceinline__ float softplus_f(float x) {
    return log1pf(expf(x));   // x in (0,1): no overflow
}
__device__ __forceinline__ float sigmoid_f(float x) {
    return 1.0f / (1.0f + expf(-x));
}

__device__ __forceinline__ float eval_pt(float x, float y, float z,
                                         const float4& q0, const float4& q1,
                                         const float4& q2)
{
    const float e0 = x - q0.x;
    const float e1 = y - q0.y;
    const float e2 = z - q0.z;
    const float z0 = e0 * q0.w;
    const float z1 = fmaf(-q1.x, z0, e1) * q1.y;
    const float z2 = fmaf(-q1.w, z1, fmaf(-q1.z, z0, e2)) * q2.x;
    const float maha = fmaf(z0, z0, fmaf(z1, z1, z2 * z2));
    return __expf(fmaf(-0.5f, maha, q2.y));
}

// Fused: per-block redundant param computation (waves 0/1) + streaming.
// Block b covers points [b*1024, (b+1)*1024) -> rows r0 and possibly r0+1.
__global__ __launch_bounds__(256) void mvn_fused_kernel(
    const float* __restrict__ rep,    // (B, 64)
    const float* __restrict__ dxyz,   // (B, NPTS, 3)
    const float* __restrict__ Wm,     // (3, 64)
    const float* __restrict__ bm,     // (3,)
    const float* __restrict__ Ws,     // (6, 64)
    const float* __restrict__ bs,     // (6,)
    float* __restrict__ out)          // (B, NPTS)
{
    const unsigned tid  = threadIdx.x;
    const unsigned gid  = blockIdx.x * 256u + tid;
    const unsigned wave = tid >> 6;
    const unsigned lane = tid & 63u;

    // ---- issue streaming loads first (latency overlaps param compute) ----
    const float4* __restrict__ src4 = (const float4*)dxyz + (size_t)gid * 3u;
    const float4 a = src4[0];
    const float4 b = src4[1];
    const float4 c = src4[2];

    // ---- per-thread row bookkeeping ----
    const unsigned p0  = gid * 4u;
    const unsigned row = p0 / NPTS;                       // magic-mul
    const unsigned rem = p0 - row * NPTS;
    const unsigned r0  = (blockIdx.x * 1024u) / NPTS;     // block's first row
    const unsigned idx = row - r0;                        // 0 or 1

    // params for rows r0, r0+1: 12 floats each
    // layout: (m0,m1,m2,iL00) (L10,iL11,L20,L21) (iL22,c,0,0)
    __shared__ float P[2][12];

    if (wave < 2) {
        const unsigned prow = (wave == 0u) ? r0 : min(r0 + 1u, (unsigned)(BATCH - 1));
        const float r = rep[(size_t)prow * DMODEL + lane];

        float d0 = r * Wm[0*64 + lane];
        float d1 = r * Wm[1*64 + lane];
        float d2 = r * Wm[2*64 + lane];
        float s0 = r * Ws[0*64 + lane];
        float s1 = r * Ws[1*64 + lane];
        float s2 = r * Ws[2*64 + lane];
        float s3 = r * Ws[3*64 + lane];
        float s4 = r * Ws[4*64 + lane];
        float s5 = r * Ws[5*64 + lane];

        d0 = wave_reduce_sum64(d0);
        d1 = wave_reduce_sum64(d1);
        d2 = wave_reduce_sum64(d2);
        s0 = wave_reduce_sum64(s0);
        s1 = wave_reduce_sum64(s1);
        s2 = wave_reduce_sum64(s2);
        s3 = wave_reduce_sum64(s3);
        s4 = wave_reduce_sum64(s4);
        s5 = wave_reduce_sum64(s5);

        if (lane == 0) {
            const float m0 = d0 + bm[0];
            const float m1 = d1 + bm[1];
            const float m2 = d2 + bm[2];

            const float L00 = softplus_f(sigmoid_f(s0 + bs[0]));
            const float L10 = sigmoid_f(s1 + bs[1]);
            const float L11 = softplus_f(sigmoid_f(s2 + bs[2]));
            const float L20 = sigmoid_f(s3 + bs[3]);
            const float L21 = sigmoid_f(s4 + bs[4]);
            const float L22 = softplus_f(sigmoid_f(s5 + bs[5]));

            const float cc = -(logf(L00) + logf(L11) + logf(L22)) - C_15LOG2PI;

            float* Pw = P[wave];
            Pw[0] = m0;         Pw[1] = m1;   Pw[2] = m2;   Pw[3] = 1.0f / L00;
            Pw[4] = L10;        Pw[5] = 1.0f / L11;
            Pw[6] = L20;        Pw[7] = L21;
            Pw[8] = 1.0f / L22; Pw[9] = cc;   Pw[10] = 0.0f; Pw[11] = 0.0f;
        }
    }
    __syncthreads();

    const float4* Pq = (const float4*)P[idx];
    const float4 q0 = Pq[0], q1 = Pq[1], q2 = Pq[2];

    float o0, o1, o2, o3;
    if (rem <= NPTS - 4u) {
        // all 4 points in this row (common case)
        o0 = eval_pt(a.x, a.y, a.z, q0, q1, q2);
        o1 = eval_pt(a.w, b.x, b.y, q0, q1, q2);
        o2 = eval_pt(b.z, b.w, c.x, q0, q1, q2);
        o3 = eval_pt(c.y, c.z, c.w, q0, q1, q2);
    } else {
        // spans a row boundary (at most one per block; here idx==0, next is P[1])
        const float4* Rq = (const float4*)P[idx + 1];
        const float4 r0q = Rq[0], r1q = Rq[1], r2q = Rq[2];
        const float4 u0 = (rem + 0u < NPTS) ? q0 : r0q;
        const float4 u1 = (rem + 0u < NPTS) ? q1 : r1q;
        const float4 u2 = (rem + 0u < NPTS) ? q2 : r2q;
        o0 = eval_pt(a.x, a.y, a.z, u0, u1, u2);
        const float4 v0 = (rem + 1u < NPTS) ? q0 : r0q;
        const float4 v1 = (rem + 1u < NPTS) ? q1 : r1q;
        const float4 v2 = (rem + 1u < NPTS) ? q2 : r2q;
        o1 = eval_pt(a.w, b.x, b.y, v0, v1, v2);
        const float4 w0 = (rem + 2u < NPTS) ? q0 : r0q;
        const float4 w1 = (rem + 2u < NPTS) ? q1 : r1q;
        const float4 w2 = (rem + 2u < NPTS) ? q2 : r2q;
        o2 = eval_pt(b.z, b.w, c.x, w0, w1, w2);
        o3 = eval_pt(c.y, c.z, c.w, r0q, r1q, r2q);  // rem+3 >= NPTS here
    }

    ((float4*)out)[gid] = make_float4(o0, o1, o2, o3);
}

extern "C" void kernel_launch(void* const* d_in, const int* in_sizes, int n_in,
                              void* d_out, int out_size, void* d_ws, size_t ws_size,
                              hipStream_t stream) {
    const float* rep  = (const float*)d_in[0];
    const float* dxyz = (const float*)d_in[1];
    const float* Wm   = (const float*)d_in[2];
    const float* bm   = (const float*)d_in[3];
    const float* Ws   = (const float*)d_in[4];
    const float* bs   = (const float*)d_in[5];
    float* out = (float*)d_out;

    mvn_fused_kernel<<<STREAM_BLOCKS, 256, 0, stream>>>(rep, dxyz, Wm, bm, Ws, bs, out);
}